// Round 1
// baseline (276.628 us; speedup 1.0000x reference)
//
#include <hip/hip_runtime.h>
#include <hip/hip_bf16.h>

// out[m][n] = sum_k x[m][k] * W[n][k] + b[n]
// M=1024, N=32768, K=512, fp32 in/out, bf16 MFMA compute.

typedef __bf16 bf16x8 __attribute__((ext_vector_type(8)));
typedef __bf16 bf16x4 __attribute__((ext_vector_type(4)));
typedef float  f32x4  __attribute__((ext_vector_type(4)));

#define MM 1024
#define NN 32768
#define KDIM 512
#define BM 128
#define BN 128
#define BK 64
#define LDT 72   // padded LDS row length in bf16 elements (144 B = 36 banks -> 2-way max, free)

__global__ __launch_bounds__(256, 2)
void gemm_bias_bf16(const float* __restrict__ X, const float* __restrict__ W,
                    const float* __restrict__ Bv, float* __restrict__ Out)
{
    __shared__ __bf16 As[BM * LDT];
    __shared__ __bf16 Bs[BN * LDT];

    const int tid  = threadIdx.x;
    const int lane = tid & 63;
    const int wave = tid >> 6;
    const int wr   = wave >> 1;     // wave row (0..1), 64 rows each
    const int wc   = wave & 1;      // wave col (0..1), 64 cols each
    const int ln15 = lane & 15;
    const int quad = lane >> 4;

    // XCD-aware swizzle: blk bits [2:0]=xcd, [5:3]=bm, [10:6]=bn_local.
    // 8 bm-blocks sharing a W-tile are adjacent in one XCD's dispatch order.
    const int blk = blockIdx.x;
    const int xcd = blk & 7;
    const int bm  = (blk >> 3) & 7;           // 0..7   (M / 128)
    const int bn  = xcd * 32 + (blk >> 6);    // 0..255 (N / 128)

    // ---- staging addresses: thread handles float4 chunk f = i*256 + tid ----
    // row = i*16 + (tid>>4), col4 = (tid&15)*4  (within the 128x64 tile)
    const int r0 = tid >> 4;
    const int c4 = (tid & 15) << 2;
    const float* aG = X + (size_t)(bm * BM + r0) * KDIM + c4;
    const float* bG = W + (size_t)(bn * BN + r0) * KDIM + c4;
    __bf16* aS = &As[r0 * LDT + c4];
    __bf16* bS = &Bs[r0 * LDT + c4];

    // ---- fragment read bases (A/B both [row][k] contiguous-k layout) ----
    const int aBase = (wr * 64 + ln15) * LDT + quad * 8;
    const int bBase = (wc * 64 + ln15) * LDT + quad * 8;

    f32x4 acc[4][4];
#pragma unroll
    for (int i = 0; i < 4; ++i)
#pragma unroll
        for (int j = 0; j < 4; ++j)
            acc[i][j] = (f32x4){0.f, 0.f, 0.f, 0.f};

#pragma unroll 1
    for (int kt = 0; kt < KDIM / BK; ++kt) {
        // global fp32 loads (issue before barrier so latency overlaps prior MFMA)
        float4 av[8], bv[8];
#pragma unroll
        for (int i = 0; i < 8; ++i) {
            av[i] = *(const float4*)(aG + (size_t)i * 16 * KDIM);
            bv[i] = *(const float4*)(bG + (size_t)i * 16 * KDIM);
        }
        aG += BK; bG += BK;

        __syncthreads();   // previous iteration's LDS reads done
#pragma unroll
        for (int i = 0; i < 8; ++i) {
            bf16x4 a4, b4;
            a4[0] = (__bf16)av[i].x; a4[1] = (__bf16)av[i].y;
            a4[2] = (__bf16)av[i].z; a4[3] = (__bf16)av[i].w;
            b4[0] = (__bf16)bv[i].x; b4[1] = (__bf16)bv[i].y;
            b4[2] = (__bf16)bv[i].z; b4[3] = (__bf16)bv[i].w;
            *(bf16x4*)(aS + i * 16 * LDT) = a4;
            *(bf16x4*)(bS + i * 16 * LDT) = b4;
        }
        __syncthreads();   // tiles ready

        // ---- MFMA inner loop: 2 k-steps of 32, 4x4 tiles of 16x16x32 ----
#pragma unroll
        for (int kk = 0; kk < 2; ++kk) {
            bf16x8 af[4], bf[4];
#pragma unroll
            for (int i = 0; i < 4; ++i)
                af[i] = *(const bf16x8*)(&As[aBase + kk * 32 + i * 16 * LDT]);
#pragma unroll
            for (int j = 0; j < 4; ++j)
                bf[j] = *(const bf16x8*)(&Bs[bBase + kk * 32 + j * 16 * LDT]);
#pragma unroll
            for (int i = 0; i < 4; ++i)
#pragma unroll
                for (int j = 0; j < 4; ++j)
                    acc[i][j] = __builtin_amdgcn_mfma_f32_16x16x32_bf16(
                        af[i], bf[j], acc[i][j], 0, 0, 0);
        }
    }

    // ---- epilogue: C/D layout col=lane&15, row=quad*4+reg ----
    const int n0 = bn * BN + wc * 64 + ln15;
    const int m0 = bm * BM + wr * 64 + quad * 4;
    float bias[4];
#pragma unroll
    for (int j = 0; j < 4; ++j) bias[j] = Bv[n0 + j * 16];

#pragma unroll
    for (int i = 0; i < 4; ++i) {
#pragma unroll
        for (int r = 0; r < 4; ++r) {
            float* o = Out + (size_t)(m0 + i * 16 + r) * NN + n0;
#pragma unroll
            for (int j = 0; j < 4; ++j)
                o[j * 16] = acc[i][j][r] + bias[j];
        }
    }
}

extern "C" void kernel_launch(void* const* d_in, const int* in_sizes, int n_in,
                              void* d_out, int out_size, void* d_ws, size_t ws_size,
                              hipStream_t stream) {
    const float* x  = (const float*)d_in[0];
    const float* W  = (const float*)d_in[1];
    const float* b  = (const float*)d_in[2];
    float* out = (float*)d_out;
    const int grid = (MM / BM) * (NN / BN);   // 8 * 256 = 2048
    gemm_bias_bf16<<<dim3(grid), dim3(256), 0, stream>>>(x, W, b, out);
}

// Round 2
// 233.939 us; speedup vs baseline: 1.1825x; 1.1825x over previous
//
#include <hip/hip_runtime.h>
#include <hip/hip_bf16.h>

// out[m][n] = sum_k x[m][k] * W[n][k] + b[n]
// M=1024, N=32768, K=512, fp32 in/out.
// Two-phase: (1) convert W,x to bf16 in d_ws; (2) m97-structure MFMA GEMM
// with global_load_lds(16B) staging and XOR-swizzled LDS chunks.

typedef __bf16 bf16x8 __attribute__((ext_vector_type(8)));
typedef __bf16 bf16x4 __attribute__((ext_vector_type(4)));
typedef float  f32x4  __attribute__((ext_vector_type(4)));

#define MM 1024
#define NN 32768
#define KD 512
#define BM 128
#define BN 128
#define BK 64

#define WB_BYTES ((size_t)NN * KD * 2)              // 33,554,432
#define XB_BYTES ((size_t)MM * KD * 2)              // 1,048,576
#define WS_NEED  (WB_BYTES + XB_BYTES)

// ---------------------------------------------------------------------------
// Phase 1: fp32 -> bf16 conversion of W (64 MB) and x (2 MB). Memory-bound.
// ---------------------------------------------------------------------------
__global__ __launch_bounds__(256)
void convert_to_bf16(const float* __restrict__ W, const float* __restrict__ X,
                     __bf16* __restrict__ Wb, __bf16* __restrict__ Xb)
{
    const int WCH = (NN * KD) / 8;   // 2,097,152 chunks of 8 floats
    const int XCH = (MM * KD) / 8;   //    65,536
    int stride = gridDim.x * blockDim.x;
    for (int c = blockIdx.x * blockDim.x + threadIdx.x; c < WCH + XCH; c += stride) {
        const float* src; __bf16* dst; int cc;
        if (c < WCH) { src = W; dst = Wb; cc = c; }
        else         { src = X; dst = Xb; cc = c - WCH; }
        f32x4 v0 = *(const f32x4*)(src + (size_t)cc * 8);
        f32x4 v1 = *(const f32x4*)(src + (size_t)cc * 8 + 4);
        bf16x8 o;
        o[0]=(__bf16)v0[0]; o[1]=(__bf16)v0[1]; o[2]=(__bf16)v0[2]; o[3]=(__bf16)v0[3];
        o[4]=(__bf16)v1[0]; o[5]=(__bf16)v1[1]; o[6]=(__bf16)v1[2]; o[7]=(__bf16)v1[3];
        *(bf16x8*)(dst + (size_t)cc * 8) = o;
    }
}

// ---------------------------------------------------------------------------
// Phase 2: bf16 GEMM, m97 structure. LDS tile layout: [row][BK] row-major,
// 16B chunks XOR-swizzled by (row&7) via the GLOBAL source address (the LDS
// destination of global_load_lds is fixed at wave-base + lane*16).
// ---------------------------------------------------------------------------
__global__ __launch_bounds__(256, 4)
void gemm_bf16_lds(const __bf16* __restrict__ Xb, const __bf16* __restrict__ Wb,
                   const float* __restrict__ Bv, float* __restrict__ Out)
{
    __shared__ __bf16 As[BM * BK];   // 16 KB
    __shared__ __bf16 Bs[BN * BK];   // 16 KB

    const int tid  = threadIdx.x;
    const int lane = tid & 63;
    const int wave = tid >> 6;
    const int ln15 = lane & 15;
    const int quad = lane >> 4;
    const int wr   = wave >> 1;
    const int wc   = wave & 1;

    // XCD swizzle: 8 consecutive same-XCD blocks share one W tile (L2 reuse).
    const int blk = blockIdx.x;
    const int xcd = blk & 7;
    const int bm  = (blk >> 3) & 7;          // M/128 = 8
    const int bn  = xcd * 32 + (blk >> 6);   // N/128 = 256

    // staging: wave w stages segments [w*4, w*4+4) of each tile; 1 seg = 8 rows x 64k.
    const int srow   = lane >> 3;   // row within segment, 0..7
    const int chunkL = lane & 7;    // LDS 16B-chunk slot within row

    const __bf16* Ag = Xb + (size_t)(bm * BM) * KD;
    const __bf16* Bg = Wb + (size_t)(bn * BN) * KD;

    f32x4 acc[4][4];
#pragma unroll
    for (int i = 0; i < 4; ++i)
#pragma unroll
        for (int j = 0; j < 4; ++j)
            acc[i][j] = (f32x4){0.f, 0.f, 0.f, 0.f};

#pragma unroll 1
    for (int kt = 0; kt < KD / BK; ++kt) {
        const int k0 = kt * BK;
        __syncthreads();   // prior iteration's ds_reads done before overwrite
#pragma unroll
        for (int i = 0; i < 4; ++i) {
            const int seg = wave * 4 + i;
            const int row = seg * 8 + srow;
            const int gch = chunkL ^ (row & 7);      // XOR swizzle on source
            __builtin_amdgcn_global_load_lds(
                (const __attribute__((address_space(1))) void*)(Ag + (size_t)row * KD + k0 + gch * 8),
                (__attribute__((address_space(3))) void*)(As + seg * 512 + lane * 8),
                16, 0, 0);
            __builtin_amdgcn_global_load_lds(
                (const __attribute__((address_space(1))) void*)(Bg + (size_t)row * KD + k0 + gch * 8),
                (__attribute__((address_space(3))) void*)(Bs + seg * 512 + lane * 8),
                16, 0, 0);
        }
        __syncthreads();   // drains vmcnt: tiles ready

#pragma unroll
        for (int kk = 0; kk < 2; ++kk) {
            bf16x8 af[4], bfr[4];
#pragma unroll
            for (int i = 0; i < 4; ++i) {
                const int ar = wr * 64 + i * 16 + ln15;
                af[i] = *(const bf16x8*)(As + ar * 64 + (((kk * 4 + quad) ^ (ar & 7)) * 8));
            }
#pragma unroll
            for (int j = 0; j < 4; ++j) {
                const int br = wc * 64 + j * 16 + ln15;
                bfr[j] = *(const bf16x8*)(Bs + br * 64 + (((kk * 4 + quad) ^ (br & 7)) * 8));
            }
#pragma unroll
            for (int i = 0; i < 4; ++i)
#pragma unroll
                for (int j = 0; j < 4; ++j)
                    acc[i][j] = __builtin_amdgcn_mfma_f32_16x16x32_bf16(
                        af[i], bfr[j], acc[i][j], 0, 0, 0);
        }
    }

    // epilogue: C/D layout col=lane&15, row=quad*4+reg  (verified round 1)
    const int n0 = bn * BN + wc * 64 + ln15;
    const int m0 = bm * BM + wr * 64 + quad * 4;
    float bias[4];
#pragma unroll
    for (int j = 0; j < 4; ++j) bias[j] = Bv[n0 + j * 16];

#pragma unroll
    for (int i = 0; i < 4; ++i) {
#pragma unroll
        for (int r = 0; r < 4; ++r) {
            float* o = Out + (size_t)(m0 + i * 16 + r) * NN + n0;
#pragma unroll
            for (int j = 0; j < 4; ++j)
                o[j * 16] = acc[i][j][r] + bias[j];
        }
    }
}

// ---------------------------------------------------------------------------
// Fallback (round-1 kernel): fp32 staging with in-kernel convert. Used only
// if ws_size is too small for the bf16 scratch copies.
// ---------------------------------------------------------------------------
#define LDT 72
__global__ __launch_bounds__(256, 2)
void gemm_bias_fallback(const float* __restrict__ X, const float* __restrict__ W,
                        const float* __restrict__ Bv, float* __restrict__ Out)
{
    __shared__ __bf16 As[BM * LDT];
    __shared__ __bf16 Bs[BN * LDT];

    const int tid  = threadIdx.x;
    const int lane = tid & 63;
    const int wave = tid >> 6;
    const int wr   = wave >> 1;
    const int wc   = wave & 1;
    const int ln15 = lane & 15;
    const int quad = lane >> 4;

    const int blk = blockIdx.x;
    const int xcd = blk & 7;
    const int bm  = (blk >> 3) & 7;
    const int bn  = xcd * 32 + (blk >> 6);

    const int r0 = tid >> 4;
    const int c4 = (tid & 15) << 2;
    const float* aG = X + (size_t)(bm * BM + r0) * KD + c4;
    const float* bG = W + (size_t)(bn * BN + r0) * KD + c4;
    __bf16* aS = &As[r0 * LDT + c4];
    __bf16* bS = &Bs[r0 * LDT + c4];

    const int aBase = (wr * 64 + ln15) * LDT + quad * 8;
    const int bBase = (wc * 64 + ln15) * LDT + quad * 8;

    f32x4 acc[4][4];
#pragma unroll
    for (int i = 0; i < 4; ++i)
#pragma unroll
        for (int j = 0; j < 4; ++j)
            acc[i][j] = (f32x4){0.f, 0.f, 0.f, 0.f};

#pragma unroll 1
    for (int kt = 0; kt < KD / BK; ++kt) {
        float4 av[8], bv[8];
#pragma unroll
        for (int i = 0; i < 8; ++i) {
            av[i] = *(const float4*)(aG + (size_t)i * 16 * KD);
            bv[i] = *(const float4*)(bG + (size_t)i * 16 * KD);
        }
        aG += BK; bG += BK;

        __syncthreads();
#pragma unroll
        for (int i = 0; i < 8; ++i) {
            bf16x4 a4, b4;
            a4[0] = (__bf16)av[i].x; a4[1] = (__bf16)av[i].y;
            a4[2] = (__bf16)av[i].z; a4[3] = (__bf16)av[i].w;
            b4[0] = (__bf16)bv[i].x; b4[1] = (__bf16)bv[i].y;
            b4[2] = (__bf16)bv[i].z; b4[3] = (__bf16)bv[i].w;
            *(bf16x4*)(aS + i * 16 * LDT) = a4;
            *(bf16x4*)(bS + i * 16 * LDT) = b4;
        }
        __syncthreads();

#pragma unroll
        for (int kk = 0; kk < 2; ++kk) {
            bf16x8 af[4], bfr[4];
#pragma unroll
            for (int i = 0; i < 4; ++i)
                af[i] = *(const bf16x8*)(&As[aBase + kk * 32 + i * 16 * LDT]);
#pragma unroll
            for (int j = 0; j < 4; ++j)
                bfr[j] = *(const bf16x8*)(&Bs[bBase + kk * 32 + j * 16 * LDT]);
#pragma unroll
            for (int i = 0; i < 4; ++i)
#pragma unroll
                for (int j = 0; j < 4; ++j)
                    acc[i][j] = __builtin_amdgcn_mfma_f32_16x16x32_bf16(
                        af[i], bfr[j], acc[i][j], 0, 0, 0);
        }
    }

    const int n0 = bn * BN + wc * 64 + ln15;
    const int m0 = bm * BM + wr * 64 + quad * 4;
    float bias[4];
#pragma unroll
    for (int j = 0; j < 4; ++j) bias[j] = Bv[n0 + j * 16];

#pragma unroll
    for (int i = 0; i < 4; ++i) {
#pragma unroll
        for (int r = 0; r < 4; ++r) {
            float* o = Out + (size_t)(m0 + i * 16 + r) * NN + n0;
#pragma unroll
            for (int j = 0; j < 4; ++j)
                o[j * 16] = acc[i][j][r] + bias[j];
        }
    }
}

extern "C" void kernel_launch(void* const* d_in, const int* in_sizes, int n_in,
                              void* d_out, int out_size, void* d_ws, size_t ws_size,
                              hipStream_t stream) {
    const float* x = (const float*)d_in[0];
    const float* W = (const float*)d_in[1];
    const float* b = (const float*)d_in[2];
    float* out = (float*)d_out;
    const int grid = (MM / BM) * (NN / BN);   // 2048

    if (ws_size >= WS_NEED) {
        __bf16* Wb = (__bf16*)d_ws;
        __bf16* Xb = (__bf16*)((char*)d_ws + WB_BYTES);
        convert_to_bf16<<<dim3(4096), dim3(256), 0, stream>>>(W, x, Wb, Xb);
        gemm_bf16_lds<<<dim3(grid), dim3(256), 0, stream>>>(Xb, Wb, b, out);
    } else {
        gemm_bias_fallback<<<dim3(grid), dim3(256), 0, stream>>>(x, W, b, out);
    }
}